// Round 1
// 413.496 us; speedup vs baseline: 1.0671x; 1.0671x over previous
//
#include <hip/hip_runtime.h>
#include <math.h>

#define NB 8
#define NP 19248
#define NC 81
#define NOBJ 8
#define NK 32
#define PHD 138
#define PWD 138
#define NPX (PHD * PWD)   // 19044
#define IH 550
#define IW 550
#define NBLK 76           // ceil(NP/256)

typedef short v8s __attribute__((ext_vector_type(8)));
typedef float v4f __attribute__((ext_vector_type(4)));

__device__ __forceinline__ float wave_sum(float v) {
  #pragma unroll
  for (int o = 32; o >= 1; o >>= 1) v += __shfl_xor(v, o);
  return v;
}
__device__ __forceinline__ int wave_sum_i(int v) {
  #pragma unroll
  for (int o = 32; o >= 1; o >>= 1) v += __shfl_xor(v, o);
  return v;
}
__device__ __forceinline__ unsigned short f2bf(float f) {
  unsigned u = __float_as_uint(f);
  u = (u + 0x7fffu + ((u >> 16) & 1u)) >> 16;
  return (unsigned short)u;
}

// grid (76, NB): one prior per thread. Per-prior max/arg + per-gt argmax via packed u64 atomicMax.
__global__ __launch_bounds__(256) void match1_kernel(
    const float* __restrict__ priors, const float* __restrict__ box_gt,
    float* __restrict__ prior_max, int* __restrict__ prior_arg,
    unsigned long long* __restrict__ forced)
{
  int b = blockIdx.y, tid = threadIdx.x;
  int p = blockIdx.x * 256 + tid;
  int lane = tid & 63;
  __shared__ float gx1[NOBJ], gy1[NOBJ], gx2[NOBJ], gy2[NOBJ], garea[NOBJ];
  if (tid < NOBJ) {
    const float* g = box_gt + (b * NOBJ + tid) * 4;
    float x1 = g[0], y1 = g[1], x2 = g[2], y2 = g[3];
    gx1[tid] = x1; gy1[tid] = y1; gx2[tid] = x2; gy2[tid] = y2;
    garea[tid] = (x2 - x1) * (y2 - y1);
  }
  __syncthreads();

  bool act = p < NP;
  float dx1 = 0, dy1 = 0, dx2 = 0, dy2 = 0, darea = 1.f;
  if (act) {
    const float* pr = priors + p * 4;
    float cx = pr[0], cy = pr[1], w = pr[2], h = pr[3];
    dx1 = cx - w * 0.5f; dy1 = cy - h * 0.5f;
    dx2 = cx + w * 0.5f; dy2 = cy + h * 0.5f;
    darea = (dx2 - dx1) * (dy2 - dy1);
  }
  float pmax = -1.f; int parg = 0;
  unsigned long long pk[NOBJ];
  #pragma unroll
  for (int j = 0; j < NOBJ; j++) {
    float ix = fmaxf(fminf(gx2[j], dx2) - fmaxf(gx1[j], dx1), 0.f);
    float iy = fmaxf(fminf(gy2[j], dy2) - fmaxf(gy1[j], dy1), 0.f);
    float inter = ix * iy;
    float iou = inter / (garea[j] + darea - inter);
    if (j == 0) { pmax = iou; parg = 0; }
    else if (iou > pmax) { pmax = iou; parg = j; }   // strict > : first-index tie-break
    pk[j] = act ? ((((unsigned long long)__float_as_uint(iou)) << 32)
                   | (unsigned long long)(0x7fffffffu - (unsigned)p))
                : 0ull;
  }
  if (act) {
    prior_max[b * NP + p] = pmax;
    prior_arg[b * NP + p] = parg;
  }
  #pragma unroll
  for (int j = 0; j < NOBJ; j++) {
    unsigned long long v = pk[j];
    #pragma unroll
    for (int o = 32; o >= 1; o >>= 1) {
      unsigned long long ov = __shfl_xor(v, o);
      if (ov > v) v = ov;
    }
    if (lane == 0) atomicMax(&forced[b * NOBJ + j], v);
  }
}

// grid (76, NB): forced-match override (later j wins) + conf + smooth-L1 box loss + block pos count.
__global__ __launch_bounds__(256) void conf_kernel(
    const float* __restrict__ priors, const float* __restrict__ box_gt,
    const int* __restrict__ class_gt, const float* __restrict__ box_p,
    const float* __restrict__ prior_max, int* __restrict__ prior_arg,
    const unsigned long long* __restrict__ forced,
    int* __restrict__ conf, int* __restrict__ blkcnt, float* accum)
{
  int b = blockIdx.y, bx = blockIdx.x, tid = threadIdx.x;
  int p = bx * 256 + tid;
  int lane = tid & 63, wid = tid >> 6;
  __shared__ int s_fi[NOBJ];
  __shared__ float lbw[4];
  __shared__ int pcw[4];
  if (tid < NOBJ)
    s_fi[tid] = 0x7fffffff - (int)(forced[b * NOBJ + tid] & 0xffffffffull);
  __syncthreads();
  float lb = 0.f;
  bool flag = false;
  if (p < NP) {
    float m = prior_max[b * NP + p];
    int j = prior_arg[b * NP + p];
    int ov = -1;
    #pragma unroll
    for (int jj = 0; jj < NOBJ; jj++)
      if (p == s_fi[jj]) ov = jj;      // later j wins
    if (ov >= 0) { m = 2.0f; j = ov; prior_arg[b * NP + p] = ov; }
    int cf = class_gt[b * NOBJ + j] + 1;
    if (m < 0.5f) cf = -1;
    if (m < 0.4f) cf = 0;
    conf[b * NP + p] = cf;
    flag = cf > 0;
    if (flag) {
      const float* g = box_gt + (b * NOBJ + j) * 4;
      float x1 = g[0], y1 = g[1], x2 = g[2], y2 = g[3];
      const float* pr = priors + p * 4;
      float pcx = pr[0], pcy = pr[1], prw = pr[2], prh = pr[3];
      float o4[4];
      o4[0] = ((x1 + x2) * 0.5f - pcx) / (0.1f * prw);
      o4[1] = ((y1 + y2) * 0.5f - pcy) / (0.1f * prh);
      o4[2] = logf((x2 - x1) / prw) / 0.2f;
      o4[3] = logf((y2 - y1) / prh) / 0.2f;
      const float* bp = box_p + (b * NP + p) * 4;
      #pragma unroll
      for (int c = 0; c < 4; c++) {
        float d = fabsf(bp[c] - o4[c]);
        lb += (d < 1.f) ? 0.5f * d * d : d - 0.5f;
      }
    }
  }
  unsigned long long bm = __ballot(flag);
  lb = wave_sum(lb);
  if (lane == 0) { lbw[wid] = lb; pcw[wid] = __popcll(bm); }
  __syncthreads();
  if (tid == 0) {
    atomicAdd(&accum[0], lbw[0] + lbw[1] + lbw[2] + lbw[3]);
    blkcnt[b * NBLK + bx] = pcw[0] + pcw[1] + pcw[2] + pcw[3];
  }
}

// grid (76, NB): ordered compaction using blkcnt prefix; last block writes npos/nneg/scale.
__global__ __launch_bounds__(256) void scatter_kernel(
    const int* __restrict__ conf, const int* __restrict__ blkcnt,
    int* __restrict__ pos_list, int* __restrict__ npos_arr,
    int* __restrict__ nneg_arr, float* __restrict__ scale_arr)
{
  int bx = blockIdx.x, b = blockIdx.y, tid = threadIdx.x;
  int lane = tid & 63, wid = tid >> 6;
  __shared__ int s_pre;
  __shared__ int wc[4];
  if (tid < 64) {
    int s = 0;
    if (tid < bx) s += blkcnt[b * NBLK + tid];
    int t2 = tid + 64;
    if (t2 < bx) s += blkcnt[b * NBLK + t2];
    s = wave_sum_i(s);
    if (tid == 0) s_pre = s;
  }
  int p = bx * 256 + tid;
  bool flag = (p < NP) && (conf[b * NP + p] > 0);
  unsigned long long m = __ballot(flag);
  if (lane == 0) wc[wid] = __popcll(m);
  __syncthreads();
  int base = s_pre;
  for (int w = 0; w < wid; w++) base += wc[w];
  int idx = base + __popcll(m & ((1ull << lane) - 1ull));
  if (flag && idx < 128) pos_list[b * 128 + idx] = p;
  if (bx == NBLK - 1 && tid == 0) {
    int np = s_pre + wc[0] + wc[1] + wc[2] + wc[3];
    npos_arr[b] = np;
    int nn = 3 * np; if (nn > NP - 1) nn = NP - 1;
    nneg_arr[b] = nn;
    scale_arr[b] = (np > 100) ? (float)np / 100.0f : 1.0f;
  }
}

// 16 lanes per row, 4 rows per wave, 16 rows per block. NB*NP = 153984 = 16*9624 exactly.
__global__ __launch_bounds__(256) void mark_kernel(
    const float* __restrict__ class_p, const int* __restrict__ conf,
    float* __restrict__ marks, float* accum)
{
  int lane = threadIdx.x & 63, wv = threadIdx.x >> 6;
  int sub = lane & 15, grp = lane >> 4;
  int row = blockIdx.x * 16 + wv * 4 + grp;
  const float* cp = class_p + (size_t)row * NC;
  float v[6];
  #pragma unroll
  for (int k = 0; k < 6; k++) {
    int c = sub + 16 * k;
    v[k] = (c < NC) ? cp[c] : -INFINITY;
  }
  float m = v[0];
  #pragma unroll
  for (int k = 1; k < 6; k++) m = fmaxf(m, v[k]);
  #pragma unroll
  for (int o = 1; o < 16; o <<= 1) m = fmaxf(m, __shfl_xor(m, o));
  float s = 0.f;
  #pragma unroll
  for (int k = 0; k < 6; k++) s += __expf(v[k] - m);
  #pragma unroll
  for (int o = 1; o < 16; o <<= 1) s += __shfl_xor(s, o);
  float lse = m + __logf(s);
  if (sub == 0) {
    int cf = conf[row];
    marks[row] = (cf != 0) ? 0.f : (lse - v[0]);
    if (cf > 0) atomicAdd(&accum[1], lse - cp[cf]);
  }
}

// Per batch, 256 threads x 76 regs: 31-step binary search on uint bits; sum of top-k marks.
__global__ __launch_bounds__(256) void select_kernel(
    const float* __restrict__ marks, const int* __restrict__ nneg_arr, float* accum)
{
  int b = blockIdx.x, tid = threadIdx.x;
  int lane = tid & 63, wid = tid >> 6;
  float v[NBLK];
  #pragma unroll
  for (int i = 0; i < NBLK; i++) {
    int p = i * 256 + tid;
    v[i] = (p < NP) ? marks[b * NP + p] : 0.f;  // pad 0: midpoints > 0, pads never counted
  }
  int k = nneg_arr[b];
  __shared__ unsigned slo, shi;
  __shared__ int wred[4];
  __shared__ float fred[4];
  if (tid == 0) { slo = 0u; shi = 0x7f800000u; }
  __syncthreads();
  while (true) {
    unsigned lo = slo, hi = shi;
    if (hi - lo <= 1u) break;
    unsigned mid = lo + ((hi - lo) >> 1);
    float fmid = __uint_as_float(mid);
    int cnt = 0;
    #pragma unroll
    for (int i = 0; i < NBLK; i++) cnt += (v[i] >= fmid) ? 1 : 0;
    cnt = wave_sum_i(cnt);
    if (lane == 0) wred[wid] = cnt;
    __syncthreads();
    if (tid == 0) {
      int tot = wred[0] + wred[1] + wred[2] + wred[3];
      if (tot >= k) slo = mid; else shi = mid;
    }
    __syncthreads();
  }
  float thr = __uint_as_float(slo);
  float s = 0.f;
  #pragma unroll
  for (int i = 0; i < NBLK; i++) if (v[i] >= thr) s += v[i];
  s = wave_sum(s);
  if (lane == 0) fred[wid] = s;
  __syncthreads();
  if (tid == 0) atomicAdd(&accum[1], fred[0] + fred[1] + fred[2] + fred[3]);
}

// Separable antialiased resize, vertical-first. Block per (oy, bn): coalesced row loads,
// 550-wide tmp in LDS, then 138 horizontal outputs -> byte plane.
__global__ __launch_bounds__(256) void resize_kernel(
    const float* __restrict__ mask_gt, unsigned char* __restrict__ dmp)
{
  int oy = blockIdx.x, bn = blockIdx.y, tid = threadIdx.x;
  __shared__ float tmp[IW];
  const float ks = (float)IH / (float)PHD;  // 550/138 ~ 3.9855
  float sy = (oy + 0.5f) * ks - 0.5f;
  int ylo = (int)ceilf(sy - ks); if (ylo < 0) ylo = 0;
  int yhi = (int)floorf(sy + ks); if (yhi > IH - 1) yhi = IH - 1;
  int ny = yhi - ylo;   // <= 7
  float wy[8];
  float wsy = 0.f;
  #pragma unroll
  for (int j = 0; j < 8; j++) {
    float w = (j <= ny) ? fmaxf(0.f, 1.f - fabsf(sy - (float)(ylo + j)) / ks) : 0.f;
    wy[j] = w; wsy += w;
  }
  const float* mg = mask_gt + (size_t)bn * (IH * IW);
  for (int x = tid; x < IW; x += 256) {
    float a = 0.f;
    #pragma unroll
    for (int j = 0; j < 8; j++) {
      if (j <= ny) a += wy[j] * mg[(size_t)(ylo + j) * IW + x];
    }
    tmp[x] = a;
  }
  __syncthreads();
  if (tid < PWD) {
    int ox = tid;
    float sx = (ox + 0.5f) * ks - 0.5f;
    int xlo = (int)ceilf(sx - ks); if (xlo < 0) xlo = 0;
    int xhi = (int)floorf(sx + ks); if (xhi > IW - 1) xhi = IW - 1;
    int nx = xhi - xlo;   // <= 7
    float wsx = 0.f, vsum = 0.f;
    #pragma unroll
    for (int i = 0; i < 8; i++) {
      float w = (i <= nx) ? fmaxf(0.f, 1.f - fabsf(sx - (float)(xlo + i)) / ks) : 0.f;
      wsx += w;
      vsum += w * tmp[xlo + i];
    }
    dmp[(size_t)bn * NPX + oy * PWD + ox] = (vsum > 0.5f * wsy * wsx) ? 1 : 0;
  }
}

// MFMA mask loss v2: 128 px/block (2 pixel-subtiles per wave), softplus-based BCE
// (2 trans ops vs 4 incl log1pf libcall), wave-uniform skip of all-out-of-box
// iterations, dead-tile skip when mb < 112.
// Out-of-box / invalid lanes: l_eff = -1e30 => sp = 0 => terms collapse to the
// reference's clamp constants exactly (p clipped to [1e-7, 0.99999988]).
__global__ __launch_bounds__(256) void maskloss_kernel(
    const float* __restrict__ proto_p, const float* __restrict__ coef_p,
    const float* __restrict__ box_gt, const int* __restrict__ pmi,
    const unsigned char* __restrict__ dmp, const int* __restrict__ pos_list,
    const int* __restrict__ npos_arr, const float* __restrict__ scale_arr,
    float* accum)
{
  int b = blockIdx.y, tid = threadIdx.x;
  int wv = tid >> 6, lane = tid & 63;
  __shared__ unsigned short s_coef[112 * NK];  // bf16 bits
  __shared__ float s_x1[112], s_x2[112], s_y1[112], s_y2[112], s_inv[112];
  __shared__ int s_gi[112];
  __shared__ unsigned char s_gtb[128];
  __shared__ float fr[4];
  int np = npos_arr[b];
  int mb = np < 100 ? np : 100;

  // 112*32 = 3584 = 14*256 exactly: explicit unroll so the 14 loads overlap
  #pragma unroll
  for (int it = 0; it < 14; ++it) {
    int i = tid + it * 256;
    int kk = i >> 5, c = i & 31;
    float v = 0.f;
    if (kk < mb) {
      int p = pos_list[b * 128 + kk];
      v = coef_p[((size_t)(b * NP) + p) * NK + c];
    }
    s_coef[i] = f2bf(v);
  }
  if (tid < 112) {
    int kk = tid;
    float x1 = 0.f, x2 = 0.f, y1 = 0.f, y2 = 0.f, inv = 0.f; int gi = 0;
    if (kk < mb) {
      int p = pos_list[b * 128 + kk];
      gi = pmi[b * NP + p];
      const float* g = box_gt + (b * NOBJ + gi) * 4;
      float bx1 = g[0], by1 = g[1], bx2 = g[2], by2 = g[3];
      float ax = bx1 * 138.f, bx = bx2 * 138.f;
      x1 = fminf(ax, bx); x2 = fmaxf(ax, bx);
      x1 = fmaxf(x1 - 1.f, 0.f); x2 = fminf(x2 + 1.f, 138.f);
      float ay = by1 * 138.f, by_ = by2 * 138.f;
      y1 = fminf(ay, by_); y2 = fmaxf(ay, by_);
      y1 = fmaxf(y1 - 1.f, 0.f); y2 = fminf(y2 + 1.f, 138.f);
      inv = 1.f / ((bx2 - bx1) * (by2 - by1));
    }
    s_x1[kk] = x1; s_x2[kk] = x2; s_y1[kk] = y1; s_y2[kk] = y2;
    s_inv[kk] = inv; s_gi[kk] = gi;
  }
  int px0 = blockIdx.x * 128;
  if (tid < 128) {
    int p = px0 + tid;
    unsigned byte = 0;
    if (p < NPX) {
      #pragma unroll
      for (int n = 0; n < NOBJ; n++)
        byte |= ((unsigned)dmp[(size_t)(b * NOBJ + n) * NPX + p]) << n;
    }
    s_gtb[tid] = (unsigned char)byte;
  }
  __syncthreads();

  int m_in = lane & 15, kq = (lane >> 4) * 8;
  v8s bfr[7];
  #pragma unroll
  for (int t = 0; t < 7; ++t)
    bfr[t] = *(const v8s*)&s_coef[(t * 16 + m_in) * NK + kq];

  v8s afr[2];
  #pragma unroll
  for (int u = 0; u < 2; ++u) {
    int pixel_a = px0 + wv * 32 + u * 16 + m_in;
    if (pixel_a > NPX - 1) pixel_a = NPX - 1;
    const float4* ap = (const float4*)(proto_p + ((size_t)b * NPX + pixel_a) * NK + kq);
    float4 a0 = ap[0], a1 = ap[1];
    float f[8] = {a0.x, a0.y, a0.z, a0.w, a1.x, a1.y, a1.z, a1.w};
    #pragma unroll
    for (int j = 0; j < 8; ++j) afr[u][j] = (short)f2bf(f[j]);
  }

  // per-lane epilogue geometry: 8 (u,r) slots, hoisted out of the t-loop
  float fxa[8], fya[8], pva[8];
  int gtb[8];
  #pragma unroll
  for (int e = 0; e < 8; ++e) {
    int pl = wv * 32 + (e >> 2) * 16 + (lane >> 4) * 4 + (e & 3);
    int pixel = px0 + pl;
    int y = pixel / PWD;
    fya[e] = (float)y;
    fxa[e] = (float)(pixel - y * PWD);
    pva[e] = (pixel < NPX) ? 1.f : 0.f;
    gtb[e] = s_gtb[pl];
  }

  const float C_POS   = 16.11809565f;     // -log(1e-7): p at lower clamp, gt=1 term
  const float C_NEGHI = 15.94238515f;     // -log1p(-0.99999988f): p at upper clamp
  const float C_NEGLO = 1.00000005e-07f;  // -log1p(-1e-7f): p at lower clamp, gt=0 term

  float loss = 0.f;
  #pragma unroll
  for (int t = 0; t < 7; ++t) {
    if (t * 16 < mb) {     // dead-tile skip (uniform branch)
      int n = t * 16 + m_in;
      float x1 = s_x1[n], x2 = s_x2[n], y1 = s_y1[n], y2 = s_y2[n], inv = s_inv[n];
      int gi = s_gi[n];
      #pragma unroll
      for (int u = 0; u < 2; ++u) {
        v4f acc = {0.f, 0.f, 0.f, 0.f};
        acc = __builtin_amdgcn_mfma_f32_16x16x32_bf16(afr[u], bfr[t], acc, 0, 0, 0);
        #pragma unroll
        for (int r = 0; r < 4; ++r) {
          int e = u * 4 + r;
          float fx = fxa[e], fy = fya[e];
          bool inb = (fx >= x1) && (fx < x2) && (fy >= y1) && (fy < y2);
          float w = inv * pva[e];
          int g = (gtb[e] >> gi) & 1;
          unsigned long long mk = __ballot(inb);
          if (mk) {
            // bce = gt*min(softplus(-l), CP) + (1-gt)*clamp(softplus(l), CNL, CNH)
            // softplus(-l) = softplus(l) - l ; out-of-box lanes use l=-1e30 -> sp=0
            float l = inb ? acc[r] : -1e30f;
            float el = __expf(-fabsf(l));
            float sp = fmaxf(l, 0.f) + __logf(1.f + el);
            float t1 = fminf(sp - l, C_POS);
            float t2 = fminf(fmaxf(sp, C_NEGLO), C_NEGHI);
            loss += (g ? t1 : t2) * w;
          } else {
            // whole wave out-of-box: constant path, no transcendentals
            loss += (g ? C_POS : C_NEGLO) * w;
          }
        }
      }
    }
  }
  loss = wave_sum(loss);
  if (lane == 0) fr[wv] = loss;
  __syncthreads();
  if (tid == 0) atomicAdd(&accum[2], (fr[0] + fr[1] + fr[2] + fr[3]) * scale_arr[b]);
}

__global__ void finalize_kernel(const float* accum, float* out) {
  out[0] = 1.5f * accum[0] + accum[1] + accum[2] * (6.125f / (138.f * 138.f));
}

extern "C" void kernel_launch(void* const* d_in, const int* in_sizes, int n_in,
                              void* d_out, int out_size, void* d_ws, size_t ws_size,
                              hipStream_t stream) {
  const float* class_p  = (const float*)d_in[0];
  const float* box_p    = (const float*)d_in[1];
  const float* coef_p   = (const float*)d_in[2];
  const float* proto_p  = (const float*)d_in[3];
  const float* priors   = (const float*)d_in[4];
  const float* box_gt   = (const float*)d_in[5];
  const float* mask_gt  = (const float*)d_in[6];
  const int*   class_gt = (const int*)d_in[7];

  char* ws = (char*)d_ws;
  float* prior_max = (float*)(ws + 0);                 // NB*NP f32 = 615936 B
  int*   prior_arg = (int*)(ws + 615936);              // NB*NP i32
  int*   conf      = (int*)(ws + 1231872);             // NB*NP i32
  float* marks     = (float*)(ws + 1847808);           // NB*NP f32
  unsigned char* dmp = (unsigned char*)(ws + 2463744); // NB*NOBJ*NPX u8 = 1218816
  int*   pos_list  = (int*)(ws + 3682560);             // NB*128 i32 = 4096
  int*   npos_arr  = (int*)(ws + 3686656);             // NB i32
  int*   nneg_arr  = (int*)(ws + 3686688);             // NB i32
  float* scale_arr = (float*)(ws + 3686720);           // NB f32
  float* accum     = (float*)(ws + 3686752);           // 4 f32  (memset region start)
  unsigned long long* forced = (unsigned long long*)(ws + 3686768); // NB*NOBJ u64 = 512
  int*   blkcnt    = (int*)(ws + 3687280);             // NB*NBLK i32 = 2432
  (void)in_sizes; (void)n_in; (void)out_size; (void)ws_size;

  // zero accum (16B) + forced (512B) in one memset node
  hipMemsetAsync((void*)accum, 0, 16 + 512, stream);

  {
    dim3 g(NBLK, NB);
    match1_kernel<<<g, 256, 0, stream>>>(priors, box_gt, prior_max, prior_arg, forced);
    conf_kernel<<<g, 256, 0, stream>>>(priors, box_gt, class_gt, box_p,
                                       prior_max, prior_arg, forced, conf, blkcnt, accum);
    scatter_kernel<<<g, 256, 0, stream>>>(conf, blkcnt, pos_list,
                                          npos_arr, nneg_arr, scale_arr);
  }
  mark_kernel<<<(NB * NP) / 16, 256, 0, stream>>>(class_p, conf, marks, accum);
  select_kernel<<<NB, 256, 0, stream>>>(marks, nneg_arr, accum);
  {
    dim3 g(PHD, NB * NOBJ);
    resize_kernel<<<g, 256, 0, stream>>>(mask_gt, dmp);
  }
  {
    dim3 g((NPX + 127) / 128, NB);
    maskloss_kernel<<<g, 256, 0, stream>>>(proto_p, coef_p, box_gt, prior_arg, dmp,
                                           pos_list, npos_arr, scale_arr, accum);
  }
  finalize_kernel<<<1, 1, 0, stream>>>(accum, (float*)d_out);
}

// Round 2
// 381.189 us; speedup vs baseline: 1.1575x; 1.0848x over previous
//
#include <hip/hip_runtime.h>
#include <math.h>

#define NB 8
#define NP 19248
#define NC 81
#define NOBJ 8
#define NK 32
#define PHD 138
#define PWD 138
#define NPX (PHD * PWD)   // 19044
#define IH 550
#define IW 550
#define NBLK 76           // ceil(NP/256)

typedef short v8s __attribute__((ext_vector_type(8)));
typedef float v4f __attribute__((ext_vector_type(4)));

__device__ __forceinline__ float wave_sum(float v) {
  #pragma unroll
  for (int o = 32; o >= 1; o >>= 1) v += __shfl_xor(v, o);
  return v;
}
__device__ __forceinline__ int wave_sum_i(int v) {
  #pragma unroll
  for (int o = 32; o >= 1; o >>= 1) v += __shfl_xor(v, o);
  return v;
}
__device__ __forceinline__ unsigned short f2bf(float f) {
  unsigned u = __float_as_uint(f);
  u = (u + 0x7fffu + ((u >> 16) & 1u)) >> 16;
  return (unsigned short)u;
}

// grid (76, NB): one prior per thread. Per-prior max/arg + per-gt argmax via packed u64 atomicMax.
__global__ __launch_bounds__(256) void match1_kernel(
    const float* __restrict__ priors, const float* __restrict__ box_gt,
    float* __restrict__ prior_max, int* __restrict__ prior_arg,
    unsigned long long* __restrict__ forced)
{
  int b = blockIdx.y, tid = threadIdx.x;
  int p = blockIdx.x * 256 + tid;
  int lane = tid & 63;
  __shared__ float gx1[NOBJ], gy1[NOBJ], gx2[NOBJ], gy2[NOBJ], garea[NOBJ];
  if (tid < NOBJ) {
    const float* g = box_gt + (b * NOBJ + tid) * 4;
    float x1 = g[0], y1 = g[1], x2 = g[2], y2 = g[3];
    gx1[tid] = x1; gy1[tid] = y1; gx2[tid] = x2; gy2[tid] = y2;
    garea[tid] = (x2 - x1) * (y2 - y1);
  }
  __syncthreads();

  bool act = p < NP;
  float dx1 = 0, dy1 = 0, dx2 = 0, dy2 = 0, darea = 1.f;
  if (act) {
    const float* pr = priors + p * 4;
    float cx = pr[0], cy = pr[1], w = pr[2], h = pr[3];
    dx1 = cx - w * 0.5f; dy1 = cy - h * 0.5f;
    dx2 = cx + w * 0.5f; dy2 = cy + h * 0.5f;
    darea = (dx2 - dx1) * (dy2 - dy1);
  }
  float pmax = -1.f; int parg = 0;
  unsigned long long pk[NOBJ];
  #pragma unroll
  for (int j = 0; j < NOBJ; j++) {
    float ix = fmaxf(fminf(gx2[j], dx2) - fmaxf(gx1[j], dx1), 0.f);
    float iy = fmaxf(fminf(gy2[j], dy2) - fmaxf(gy1[j], dy1), 0.f);
    float inter = ix * iy;
    float iou = inter / (garea[j] + darea - inter);
    if (j == 0) { pmax = iou; parg = 0; }
    else if (iou > pmax) { pmax = iou; parg = j; }   // strict > : first-index tie-break
    pk[j] = act ? ((((unsigned long long)__float_as_uint(iou)) << 32)
                   | (unsigned long long)(0x7fffffffu - (unsigned)p))
                : 0ull;
  }
  if (act) {
    prior_max[b * NP + p] = pmax;
    prior_arg[b * NP + p] = parg;
  }
  #pragma unroll
  for (int j = 0; j < NOBJ; j++) {
    unsigned long long v = pk[j];
    #pragma unroll
    for (int o = 32; o >= 1; o >>= 1) {
      unsigned long long ov = __shfl_xor(v, o);
      if (ov > v) v = ov;
    }
    if (lane == 0) atomicMax(&forced[b * NOBJ + j], v);
  }
}

// grid (76, NB): forced-match override (later j wins) + conf + smooth-L1 box loss + block pos count.
__global__ __launch_bounds__(256) void conf_kernel(
    const float* __restrict__ priors, const float* __restrict__ box_gt,
    const int* __restrict__ class_gt, const float* __restrict__ box_p,
    const float* __restrict__ prior_max, int* __restrict__ prior_arg,
    const unsigned long long* __restrict__ forced,
    int* __restrict__ conf, int* __restrict__ blkcnt, float* accum)
{
  int b = blockIdx.y, bx = blockIdx.x, tid = threadIdx.x;
  int p = bx * 256 + tid;
  int lane = tid & 63, wid = tid >> 6;
  __shared__ int s_fi[NOBJ];
  __shared__ float lbw[4];
  __shared__ int pcw[4];
  if (tid < NOBJ)
    s_fi[tid] = 0x7fffffff - (int)(forced[b * NOBJ + tid] & 0xffffffffull);
  __syncthreads();
  float lb = 0.f;
  bool flag = false;
  if (p < NP) {
    float m = prior_max[b * NP + p];
    int j = prior_arg[b * NP + p];
    int ov = -1;
    #pragma unroll
    for (int jj = 0; jj < NOBJ; jj++)
      if (p == s_fi[jj]) ov = jj;      // later j wins
    if (ov >= 0) { m = 2.0f; j = ov; prior_arg[b * NP + p] = ov; }
    int cf = class_gt[b * NOBJ + j] + 1;
    if (m < 0.5f) cf = -1;
    if (m < 0.4f) cf = 0;
    conf[b * NP + p] = cf;
    flag = cf > 0;
    if (flag) {
      const float* g = box_gt + (b * NOBJ + j) * 4;
      float x1 = g[0], y1 = g[1], x2 = g[2], y2 = g[3];
      const float* pr = priors + p * 4;
      float pcx = pr[0], pcy = pr[1], prw = pr[2], prh = pr[3];
      float o4[4];
      o4[0] = ((x1 + x2) * 0.5f - pcx) / (0.1f * prw);
      o4[1] = ((y1 + y2) * 0.5f - pcy) / (0.1f * prh);
      o4[2] = logf((x2 - x1) / prw) / 0.2f;
      o4[3] = logf((y2 - y1) / prh) / 0.2f;
      const float* bp = box_p + (b * NP + p) * 4;
      #pragma unroll
      for (int c = 0; c < 4; c++) {
        float d = fabsf(bp[c] - o4[c]);
        lb += (d < 1.f) ? 0.5f * d * d : d - 0.5f;
      }
    }
  }
  unsigned long long bm = __ballot(flag);
  lb = wave_sum(lb);
  if (lane == 0) { lbw[wid] = lb; pcw[wid] = __popcll(bm); }
  __syncthreads();
  if (tid == 0) {
    atomicAdd(&accum[0], lbw[0] + lbw[1] + lbw[2] + lbw[3]);
    blkcnt[b * NBLK + bx] = pcw[0] + pcw[1] + pcw[2] + pcw[3];
  }
}

// grid (76, NB): ordered compaction using blkcnt prefix; last block writes npos/nneg/scale.
__global__ __launch_bounds__(256) void scatter_kernel(
    const int* __restrict__ conf, const int* __restrict__ blkcnt,
    int* __restrict__ pos_list, int* __restrict__ npos_arr,
    int* __restrict__ nneg_arr, float* __restrict__ scale_arr)
{
  int bx = blockIdx.x, b = blockIdx.y, tid = threadIdx.x;
  int lane = tid & 63, wid = tid >> 6;
  __shared__ int s_pre;
  __shared__ int wc[4];
  if (tid < 64) {
    int s = 0;
    if (tid < bx) s += blkcnt[b * NBLK + tid];
    int t2 = tid + 64;
    if (t2 < bx) s += blkcnt[b * NBLK + t2];
    s = wave_sum_i(s);
    if (tid == 0) s_pre = s;
  }
  int p = bx * 256 + tid;
  bool flag = (p < NP) && (conf[b * NP + p] > 0);
  unsigned long long m = __ballot(flag);
  if (lane == 0) wc[wid] = __popcll(m);
  __syncthreads();
  int base = s_pre;
  for (int w = 0; w < wid; w++) base += wc[w];
  int idx = base + __popcll(m & ((1ull << lane) - 1ull));
  if (flag && idx < 128) pos_list[b * 128 + idx] = p;
  if (bx == NBLK - 1 && tid == 0) {
    int np = s_pre + wc[0] + wc[1] + wc[2] + wc[3];
    npos_arr[b] = np;
    int nn = 3 * np; if (nn > NP - 1) nn = NP - 1;
    nneg_arr[b] = nn;
    scale_arr[b] = (np > 100) ? (float)np / 100.0f : 1.0f;
  }
}

// 16 lanes per row, 4 rows per wave, 16 rows per block. NB*NP = 153984 = 16*9624 exactly.
__global__ __launch_bounds__(256) void mark_kernel(
    const float* __restrict__ class_p, const int* __restrict__ conf,
    float* __restrict__ marks, float* accum)
{
  int lane = threadIdx.x & 63, wv = threadIdx.x >> 6;
  int sub = lane & 15, grp = lane >> 4;
  int row = blockIdx.x * 16 + wv * 4 + grp;
  const float* cp = class_p + (size_t)row * NC;
  float v[6];
  #pragma unroll
  for (int k = 0; k < 6; k++) {
    int c = sub + 16 * k;
    v[k] = (c < NC) ? cp[c] : -INFINITY;
  }
  float m = v[0];
  #pragma unroll
  for (int k = 1; k < 6; k++) m = fmaxf(m, v[k]);
  #pragma unroll
  for (int o = 1; o < 16; o <<= 1) m = fmaxf(m, __shfl_xor(m, o));
  float s = 0.f;
  #pragma unroll
  for (int k = 0; k < 6; k++) s += __expf(v[k] - m);
  #pragma unroll
  for (int o = 1; o < 16; o <<= 1) s += __shfl_xor(s, o);
  float lse = m + __logf(s);
  if (sub == 0) {
    int cf = conf[row];
    marks[row] = (cf != 0) ? 0.f : (lse - v[0]);
    if (cf > 0) atomicAdd(&accum[1], lse - cp[cf]);
  }
}

// Per batch, 256 threads x 76 regs: 31-step binary search on uint bits; sum of top-k marks.
__global__ __launch_bounds__(256) void select_kernel(
    const float* __restrict__ marks, const int* __restrict__ nneg_arr, float* accum)
{
  int b = blockIdx.x, tid = threadIdx.x;
  int lane = tid & 63, wid = tid >> 6;
  float v[NBLK];
  #pragma unroll
  for (int i = 0; i < NBLK; i++) {
    int p = i * 256 + tid;
    v[i] = (p < NP) ? marks[b * NP + p] : 0.f;  // pad 0: midpoints > 0, pads never counted
  }
  int k = nneg_arr[b];
  __shared__ unsigned slo, shi;
  __shared__ int wred[4];
  __shared__ float fred[4];
  if (tid == 0) { slo = 0u; shi = 0x7f800000u; }
  __syncthreads();
  while (true) {
    unsigned lo = slo, hi = shi;
    if (hi - lo <= 1u) break;
    unsigned mid = lo + ((hi - lo) >> 1);
    float fmid = __uint_as_float(mid);
    int cnt = 0;
    #pragma unroll
    for (int i = 0; i < NBLK; i++) cnt += (v[i] >= fmid) ? 1 : 0;
    cnt = wave_sum_i(cnt);
    if (lane == 0) wred[wid] = cnt;
    __syncthreads();
    if (tid == 0) {
      int tot = wred[0] + wred[1] + wred[2] + wred[3];
      if (tot >= k) slo = mid; else shi = mid;
    }
    __syncthreads();
  }
  float thr = __uint_as_float(slo);
  float s = 0.f;
  #pragma unroll
  for (int i = 0; i < NBLK; i++) if (v[i] >= thr) s += v[i];
  s = wave_sum(s);
  if (lane == 0) fred[wid] = s;
  __syncthreads();
  if (tid == 0) atomicAdd(&accum[1], fred[0] + fred[1] + fred[2] + fred[3]);
}

// Separable antialiased resize v2. Block = (plane-group of 4, oy). Each wave owns one
// plane: float2 row loads -> vertical reduce into a private LDS strip (no cross-wave
// dependency). Horizontal weights hoisted into LDS once per block. One barrier total.
// Arithmetic order identical to v1 -> bit-exact binary output.
__global__ __launch_bounds__(256) void resize_kernel(
    const float* __restrict__ mask_gt, unsigned char* __restrict__ dmp)
{
  int pg = blockIdx.x;         // plane group 0..15
  int oy = blockIdx.y;         // 0..137
  int tid = threadIdx.x;
  int wv = tid >> 6, lane = tid & 63;
  int bn = pg * 4 + wv;        // plane 0..63

  __shared__ float tmp[4][IW];       // per-wave vertical-pass rows (8800 B)
  __shared__ float s_wx[PWD][9];     // horizontal weights, padded stride 9 (4968 B)
  __shared__ float s_wsx[PWD];
  __shared__ int   s_xlo[PWD];

  const float ks = (float)IH / (float)PHD;  // 550/138

  // horizontal weights: once per block (threads 0..137)
  if (tid < PWD) {
    int ox = tid;
    float sx = (ox + 0.5f) * ks - 0.5f;
    int xlo = (int)ceilf(sx - ks); if (xlo < 0) xlo = 0;
    int xhi = (int)floorf(sx + ks); if (xhi > IW - 1) xhi = IW - 1;
    int nx = xhi - xlo;
    float wsx = 0.f;
    #pragma unroll
    for (int i = 0; i < 8; i++) {
      float w = (i <= nx) ? fmaxf(0.f, 1.f - fabsf(sx - (float)(xlo + i)) / ks) : 0.f;
      s_wx[ox][i] = w; wsx += w;
    }
    s_xlo[ox] = xlo;
    s_wsx[ox] = wsx;
  }

  // vertical weights: uniform across the block (same oy)
  float sy = (oy + 0.5f) * ks - 0.5f;
  int ylo = (int)ceilf(sy - ks); if (ylo < 0) ylo = 0;
  int yhi = (int)floorf(sy + ks); if (yhi > IH - 1) yhi = IH - 1;
  int ny = yhi - ylo;   // <= 7
  float wy[8]; float wsy = 0.f;
  #pragma unroll
  for (int j = 0; j < 8; j++) {
    float w = (j <= ny) ? fmaxf(0.f, 1.f - fabsf(sy - (float)(ylo + j)) / ks) : 0.f;
    wy[j] = w; wsy += w;
  }

  // vertical pass: wave wv reduces its plane's 8 rows into tmp[wv][.] with float2 loads.
  // Rows are 2200 B apart -> 8 B aligned. Clamped row index + zero weight for j > ny
  // adds exactly +0.0 (mask_gt >= 0), preserving bit-exactness.
  const float* mg = mask_gt + (size_t)bn * (IH * IW);
  const float* rowp[8];
  #pragma unroll
  for (int j = 0; j < 8; j++) {
    int y = ylo + j; if (y > IH - 1) y = IH - 1;
    rowp[j] = mg + (size_t)y * IW;
  }
  for (int x2 = lane; x2 < IW / 2; x2 += 64) {
    float ax = 0.f, ay = 0.f;
    #pragma unroll
    for (int j = 0; j < 8; j++) {
      float2 v = *(const float2*)(rowp[j] + 2 * x2);
      ax += wy[j] * v.x;
      ay += wy[j] * v.y;
    }
    tmp[wv][2 * x2]     = ax;
    tmp[wv][2 * x2 + 1] = ay;
  }
  __syncthreads();   // publish s_wx/s_wsx/s_xlo (tmp[wv] is wave-private)

  // horizontal pass + threshold: 138 outputs per wave (its own plane)
  unsigned char* op = dmp + (size_t)bn * NPX + (size_t)oy * PWD;
  for (int ox = lane; ox < PWD; ox += 64) {
    int xlo = s_xlo[ox];
    float vsum = 0.f;
    #pragma unroll
    for (int i = 0; i < 8; i++) {
      int xi = xlo + i; if (xi > IW - 1) xi = IW - 1;
      vsum += s_wx[ox][i] * tmp[wv][xi];
    }
    op[ox] = (vsum > 0.5f * wsy * s_wsx[ox]) ? 1 : 0;
  }
}

// MFMA mask loss v2: 128 px/block (2 pixel-subtiles per wave), softplus-based BCE
// (2 trans ops vs 4 incl log1pf libcall), wave-uniform skip of all-out-of-box
// iterations, dead-tile skip when mb < 112.
// Out-of-box / invalid lanes: l_eff = -1e30 => sp = 0 => terms collapse to the
// reference's clamp constants exactly (p clipped to [1e-7, 0.99999988]).
__global__ __launch_bounds__(256) void maskloss_kernel(
    const float* __restrict__ proto_p, const float* __restrict__ coef_p,
    const float* __restrict__ box_gt, const int* __restrict__ pmi,
    const unsigned char* __restrict__ dmp, const int* __restrict__ pos_list,
    const int* __restrict__ npos_arr, const float* __restrict__ scale_arr,
    float* accum)
{
  int b = blockIdx.y, tid = threadIdx.x;
  int wv = tid >> 6, lane = tid & 63;
  __shared__ unsigned short s_coef[112 * NK];  // bf16 bits
  __shared__ float s_x1[112], s_x2[112], s_y1[112], s_y2[112], s_inv[112];
  __shared__ int s_gi[112];
  __shared__ unsigned char s_gtb[128];
  __shared__ float fr[4];
  int np = npos_arr[b];
  int mb = np < 100 ? np : 100;

  // 112*32 = 3584 = 14*256 exactly: explicit unroll so the 14 loads overlap
  #pragma unroll
  for (int it = 0; it < 14; ++it) {
    int i = tid + it * 256;
    int kk = i >> 5, c = i & 31;
    float v = 0.f;
    if (kk < mb) {
      int p = pos_list[b * 128 + kk];
      v = coef_p[((size_t)(b * NP) + p) * NK + c];
    }
    s_coef[i] = f2bf(v);
  }
  if (tid < 112) {
    int kk = tid;
    float x1 = 0.f, x2 = 0.f, y1 = 0.f, y2 = 0.f, inv = 0.f; int gi = 0;
    if (kk < mb) {
      int p = pos_list[b * 128 + kk];
      gi = pmi[b * NP + p];
      const float* g = box_gt + (b * NOBJ + gi) * 4;
      float bx1 = g[0], by1 = g[1], bx2 = g[2], by2 = g[3];
      float ax = bx1 * 138.f, bx = bx2 * 138.f;
      x1 = fminf(ax, bx); x2 = fmaxf(ax, bx);
      x1 = fmaxf(x1 - 1.f, 0.f); x2 = fminf(x2 + 1.f, 138.f);
      float ay = by1 * 138.f, by_ = by2 * 138.f;
      y1 = fminf(ay, by_); y2 = fmaxf(ay, by_);
      y1 = fmaxf(y1 - 1.f, 0.f); y2 = fminf(y2 + 1.f, 138.f);
      inv = 1.f / ((bx2 - bx1) * (by2 - by1));
    }
    s_x1[kk] = x1; s_x2[kk] = x2; s_y1[kk] = y1; s_y2[kk] = y2;
    s_inv[kk] = inv; s_gi[kk] = gi;
  }
  int px0 = blockIdx.x * 128;
  if (tid < 128) {
    int p = px0 + tid;
    unsigned byte = 0;
    if (p < NPX) {
      #pragma unroll
      for (int n = 0; n < NOBJ; n++)
        byte |= ((unsigned)dmp[(size_t)(b * NOBJ + n) * NPX + p]) << n;
    }
    s_gtb[tid] = (unsigned char)byte;
  }
  __syncthreads();

  int m_in = lane & 15, kq = (lane >> 4) * 8;
  v8s bfr[7];
  #pragma unroll
  for (int t = 0; t < 7; ++t)
    bfr[t] = *(const v8s*)&s_coef[(t * 16 + m_in) * NK + kq];

  v8s afr[2];
  #pragma unroll
  for (int u = 0; u < 2; ++u) {
    int pixel_a = px0 + wv * 32 + u * 16 + m_in;
    if (pixel_a > NPX - 1) pixel_a = NPX - 1;
    const float4* ap = (const float4*)(proto_p + ((size_t)b * NPX + pixel_a) * NK + kq);
    float4 a0 = ap[0], a1 = ap[1];
    float f[8] = {a0.x, a0.y, a0.z, a0.w, a1.x, a1.y, a1.z, a1.w};
    #pragma unroll
    for (int j = 0; j < 8; ++j) afr[u][j] = (short)f2bf(f[j]);
  }

  // per-lane epilogue geometry: 8 (u,r) slots, hoisted out of the t-loop
  float fxa[8], fya[8], pva[8];
  int gtb[8];
  #pragma unroll
  for (int e = 0; e < 8; ++e) {
    int pl = wv * 32 + (e >> 2) * 16 + (lane >> 4) * 4 + (e & 3);
    int pixel = px0 + pl;
    int y = pixel / PWD;
    fya[e] = (float)y;
    fxa[e] = (float)(pixel - y * PWD);
    pva[e] = (pixel < NPX) ? 1.f : 0.f;
    gtb[e] = s_gtb[pl];
  }

  const float C_POS   = 16.11809565f;     // -log(1e-7): p at lower clamp, gt=1 term
  const float C_NEGHI = 15.94238515f;     // -log1p(-0.99999988f): p at upper clamp
  const float C_NEGLO = 1.00000005e-07f;  // -log1p(-1e-7f): p at lower clamp, gt=0 term

  float loss = 0.f;
  #pragma unroll
  for (int t = 0; t < 7; ++t) {
    if (t * 16 < mb) {     // dead-tile skip (uniform branch)
      int n = t * 16 + m_in;
      float x1 = s_x1[n], x2 = s_x2[n], y1 = s_y1[n], y2 = s_y2[n], inv = s_inv[n];
      int gi = s_gi[n];
      #pragma unroll
      for (int u = 0; u < 2; ++u) {
        v4f acc = {0.f, 0.f, 0.f, 0.f};
        acc = __builtin_amdgcn_mfma_f32_16x16x32_bf16(afr[u], bfr[t], acc, 0, 0, 0);
        #pragma unroll
        for (int r = 0; r < 4; ++r) {
          int e = u * 4 + r;
          float fx = fxa[e], fy = fya[e];
          bool inb = (fx >= x1) && (fx < x2) && (fy >= y1) && (fy < y2);
          float w = inv * pva[e];
          int g = (gtb[e] >> gi) & 1;
          unsigned long long mk = __ballot(inb);
          if (mk) {
            // bce = gt*min(softplus(-l), CP) + (1-gt)*clamp(softplus(l), CNL, CNH)
            // softplus(-l) = softplus(l) - l ; out-of-box lanes use l=-1e30 -> sp=0
            float l = inb ? acc[r] : -1e30f;
            float el = __expf(-fabsf(l));
            float sp = fmaxf(l, 0.f) + __logf(1.f + el);
            float t1 = fminf(sp - l, C_POS);
            float t2 = fminf(fmaxf(sp, C_NEGLO), C_NEGHI);
            loss += (g ? t1 : t2) * w;
          } else {
            // whole wave out-of-box: constant path, no transcendentals
            loss += (g ? C_POS : C_NEGLO) * w;
          }
        }
      }
    }
  }
  loss = wave_sum(loss);
  if (lane == 0) fr[wv] = loss;
  __syncthreads();
  if (tid == 0) atomicAdd(&accum[2], (fr[0] + fr[1] + fr[2] + fr[3]) * scale_arr[b]);
}

__global__ void finalize_kernel(const float* accum, float* out) {
  out[0] = 1.5f * accum[0] + accum[1] + accum[2] * (6.125f / (138.f * 138.f));
}

extern "C" void kernel_launch(void* const* d_in, const int* in_sizes, int n_in,
                              void* d_out, int out_size, void* d_ws, size_t ws_size,
                              hipStream_t stream) {
  const float* class_p  = (const float*)d_in[0];
  const float* box_p    = (const float*)d_in[1];
  const float* coef_p   = (const float*)d_in[2];
  const float* proto_p  = (const float*)d_in[3];
  const float* priors   = (const float*)d_in[4];
  const float* box_gt   = (const float*)d_in[5];
  const float* mask_gt  = (const float*)d_in[6];
  const int*   class_gt = (const int*)d_in[7];

  char* ws = (char*)d_ws;
  float* prior_max = (float*)(ws + 0);                 // NB*NP f32 = 615936 B
  int*   prior_arg = (int*)(ws + 615936);              // NB*NP i32
  int*   conf      = (int*)(ws + 1231872);             // NB*NP i32
  float* marks     = (float*)(ws + 1847808);           // NB*NP f32
  unsigned char* dmp = (unsigned char*)(ws + 2463744); // NB*NOBJ*NPX u8 = 1218816
  int*   pos_list  = (int*)(ws + 3682560);             // NB*128 i32 = 4096
  int*   npos_arr  = (int*)(ws + 3686656);             // NB i32
  int*   nneg_arr  = (int*)(ws + 3686688);             // NB i32
  float* scale_arr = (float*)(ws + 3686720);           // NB f32
  float* accum     = (float*)(ws + 3686752);           // 4 f32  (memset region start)
  unsigned long long* forced = (unsigned long long*)(ws + 3686768); // NB*NOBJ u64 = 512
  int*   blkcnt    = (int*)(ws + 3687280);             // NB*NBLK i32 = 2432
  (void)in_sizes; (void)n_in; (void)out_size; (void)ws_size;

  // zero accum (16B) + forced (512B) in one memset node
  hipMemsetAsync((void*)accum, 0, 16 + 512, stream);

  {
    dim3 g(NBLK, NB);
    match1_kernel<<<g, 256, 0, stream>>>(priors, box_gt, prior_max, prior_arg, forced);
    conf_kernel<<<g, 256, 0, stream>>>(priors, box_gt, class_gt, box_p,
                                       prior_max, prior_arg, forced, conf, blkcnt, accum);
    scatter_kernel<<<g, 256, 0, stream>>>(conf, blkcnt, pos_list,
                                          npos_arr, nneg_arr, scale_arr);
  }
  mark_kernel<<<(NB * NP) / 16, 256, 0, stream>>>(class_p, conf, marks, accum);
  select_kernel<<<NB, 256, 0, stream>>>(marks, nneg_arr, accum);
  {
    dim3 g(NB * NOBJ / 4, PHD);   // (plane-group, oy)
    resize_kernel<<<g, 256, 0, stream>>>(mask_gt, dmp);
  }
  {
    dim3 g((NPX + 127) / 128, NB);
    maskloss_kernel<<<g, 256, 0, stream>>>(proto_p, coef_p, box_gt, prior_arg, dmp,
                                           pos_list, npos_arr, scale_arr, accum);
  }
  finalize_kernel<<<1, 1, 0, stream>>>(accum, (float*)d_out);
}

// Round 3
// 356.316 us; speedup vs baseline: 1.2383x; 1.0698x over previous
//
#include <hip/hip_runtime.h>
#include <math.h>

#define NB 8
#define NP 19248
#define NC 81
#define NOBJ 8
#define NK 32
#define PHD 138
#define PWD 138
#define NPX (PHD * PWD)   // 19044
#define IH 550
#define IW 550
#define NBLK 76           // ceil(NP/256)
#define MROWG 9624        // (NB*NP)/16 row-groups for mark
#define MGRID 1203        // mark grid: 8 row-groups per block

typedef short v8s __attribute__((ext_vector_type(8)));
typedef float v4f __attribute__((ext_vector_type(4)));

__device__ __forceinline__ float wave_sum(float v) {
  #pragma unroll
  for (int o = 32; o >= 1; o >>= 1) v += __shfl_xor(v, o);
  return v;
}
__device__ __forceinline__ int wave_sum_i(int v) {
  #pragma unroll
  for (int o = 32; o >= 1; o >>= 1) v += __shfl_xor(v, o);
  return v;
}
__device__ __forceinline__ unsigned short f2bf(float f) {
  unsigned u = __float_as_uint(f);
  u = (u + 0x7fffu + ((u >> 16) & 1u)) >> 16;
  return (unsigned short)u;
}

// grid (76, NB): one prior per thread. Per-prior max/arg + per-gt argmax via packed u64 atomicMax.
__global__ __launch_bounds__(256) void match1_kernel(
    const float* __restrict__ priors, const float* __restrict__ box_gt,
    float* __restrict__ prior_max, int* __restrict__ prior_arg,
    unsigned long long* __restrict__ forced)
{
  int b = blockIdx.y, tid = threadIdx.x;
  int p = blockIdx.x * 256 + tid;
  int lane = tid & 63;
  __shared__ float gx1[NOBJ], gy1[NOBJ], gx2[NOBJ], gy2[NOBJ], garea[NOBJ];
  if (tid < NOBJ) {
    const float* g = box_gt + (b * NOBJ + tid) * 4;
    float x1 = g[0], y1 = g[1], x2 = g[2], y2 = g[3];
    gx1[tid] = x1; gy1[tid] = y1; gx2[tid] = x2; gy2[tid] = y2;
    garea[tid] = (x2 - x1) * (y2 - y1);
  }
  __syncthreads();

  bool act = p < NP;
  float dx1 = 0, dy1 = 0, dx2 = 0, dy2 = 0, darea = 1.f;
  if (act) {
    const float* pr = priors + p * 4;
    float cx = pr[0], cy = pr[1], w = pr[2], h = pr[3];
    dx1 = cx - w * 0.5f; dy1 = cy - h * 0.5f;
    dx2 = cx + w * 0.5f; dy2 = cy + h * 0.5f;
    darea = (dx2 - dx1) * (dy2 - dy1);
  }
  float pmax = -1.f; int parg = 0;
  unsigned long long pk[NOBJ];
  #pragma unroll
  for (int j = 0; j < NOBJ; j++) {
    float ix = fmaxf(fminf(gx2[j], dx2) - fmaxf(gx1[j], dx1), 0.f);
    float iy = fmaxf(fminf(gy2[j], dy2) - fmaxf(gy1[j], dy1), 0.f);
    float inter = ix * iy;
    float iou = inter / (garea[j] + darea - inter);
    if (j == 0) { pmax = iou; parg = 0; }
    else if (iou > pmax) { pmax = iou; parg = j; }   // strict > : first-index tie-break
    pk[j] = act ? ((((unsigned long long)__float_as_uint(iou)) << 32)
                   | (unsigned long long)(0x7fffffffu - (unsigned)p))
                : 0ull;
  }
  if (act) {
    prior_max[b * NP + p] = pmax;
    prior_arg[b * NP + p] = parg;
  }
  #pragma unroll
  for (int j = 0; j < NOBJ; j++) {
    unsigned long long v = pk[j];
    #pragma unroll
    for (int o = 32; o >= 1; o >>= 1) {
      unsigned long long ov = __shfl_xor(v, o);
      if (ov > v) v = ov;
    }
    if (lane == 0) atomicMax(&forced[b * NOBJ + j], v);
  }
}

// grid (76, NB): forced-match override (later j wins) + conf + smooth-L1 box loss + block pos count.
__global__ __launch_bounds__(256) void conf_kernel(
    const float* __restrict__ priors, const float* __restrict__ box_gt,
    const int* __restrict__ class_gt, const float* __restrict__ box_p,
    const float* __restrict__ prior_max, int* __restrict__ prior_arg,
    const unsigned long long* __restrict__ forced,
    int* __restrict__ conf, int* __restrict__ blkcnt, float* accum)
{
  int b = blockIdx.y, bx = blockIdx.x, tid = threadIdx.x;
  int p = bx * 256 + tid;
  int lane = tid & 63, wid = tid >> 6;
  __shared__ int s_fi[NOBJ];
  __shared__ float lbw[4];
  __shared__ int pcw[4];
  if (tid < NOBJ)
    s_fi[tid] = 0x7fffffff - (int)(forced[b * NOBJ + tid] & 0xffffffffull);
  __syncthreads();
  float lb = 0.f;
  bool flag = false;
  if (p < NP) {
    float m = prior_max[b * NP + p];
    int j = prior_arg[b * NP + p];
    int ov = -1;
    #pragma unroll
    for (int jj = 0; jj < NOBJ; jj++)
      if (p == s_fi[jj]) ov = jj;      // later j wins
    if (ov >= 0) { m = 2.0f; j = ov; prior_arg[b * NP + p] = ov; }
    int cf = class_gt[b * NOBJ + j] + 1;
    if (m < 0.5f) cf = -1;
    if (m < 0.4f) cf = 0;
    conf[b * NP + p] = cf;
    flag = cf > 0;
    if (flag) {
      const float* g = box_gt + (b * NOBJ + j) * 4;
      float x1 = g[0], y1 = g[1], x2 = g[2], y2 = g[3];
      const float* pr = priors + p * 4;
      float pcx = pr[0], pcy = pr[1], prw = pr[2], prh = pr[3];
      float o4[4];
      o4[0] = ((x1 + x2) * 0.5f - pcx) / (0.1f * prw);
      o4[1] = ((y1 + y2) * 0.5f - pcy) / (0.1f * prh);
      o4[2] = logf((x2 - x1) / prw) / 0.2f;
      o4[3] = logf((y2 - y1) / prh) / 0.2f;
      const float* bp = box_p + (b * NP + p) * 4;
      #pragma unroll
      for (int c = 0; c < 4; c++) {
        float d = fabsf(bp[c] - o4[c]);
        lb += (d < 1.f) ? 0.5f * d * d : d - 0.5f;
      }
    }
  }
  unsigned long long bm = __ballot(flag);
  lb = wave_sum(lb);
  if (lane == 0) { lbw[wid] = lb; pcw[wid] = __popcll(bm); }
  __syncthreads();
  if (tid == 0) {
    atomicAdd(&accum[0], lbw[0] + lbw[1] + lbw[2] + lbw[3]);
    blkcnt[b * NBLK + bx] = pcw[0] + pcw[1] + pcw[2] + pcw[3];
  }
}

// grid (76, NB): ordered compaction using blkcnt prefix; last block writes npos/nneg/scale.
__global__ __launch_bounds__(256) void scatter_kernel(
    const int* __restrict__ conf, const int* __restrict__ blkcnt,
    int* __restrict__ pos_list, int* __restrict__ npos_arr,
    int* __restrict__ nneg_arr, float* __restrict__ scale_arr)
{
  int bx = blockIdx.x, b = blockIdx.y, tid = threadIdx.x;
  int lane = tid & 63, wid = tid >> 6;
  __shared__ int s_pre;
  __shared__ int wc[4];
  if (tid < 64) {
    int s = 0;
    if (tid < bx) s += blkcnt[b * NBLK + tid];
    int t2 = tid + 64;
    if (t2 < bx) s += blkcnt[b * NBLK + t2];
    s = wave_sum_i(s);
    if (tid == 0) s_pre = s;
  }
  int p = bx * 256 + tid;
  bool flag = (p < NP) && (conf[b * NP + p] > 0);
  unsigned long long m = __ballot(flag);
  if (lane == 0) wc[wid] = __popcll(m);
  __syncthreads();
  int base = s_pre;
  for (int w = 0; w < wid; w++) base += wc[w];
  int idx = base + __popcll(m & ((1ull << lane) - 1ull));
  if (flag && idx < 128) pos_list[b * 128 + idx] = p;
  if (bx == NBLK - 1 && tid == 0) {
    int np = s_pre + wc[0] + wc[1] + wc[2] + wc[3];
    npos_arr[b] = np;
    int nn = 3 * np; if (nn > NP - 1) nn = NP - 1;
    nneg_arr[b] = nn;
    scale_arr[b] = (np > 100) ? (float)np / 100.0f : 1.0f;
  }
}

// mark v2: grid-stride over 9624 row-groups with 1203 blocks (dispatch-rate fix).
// Per-row arithmetic and lane mapping identical to v1 -> bit-identical marks.
// Positive-NLL accumulated per block, one atomic at the end.
__global__ __launch_bounds__(256) void mark_kernel(
    const float* __restrict__ class_p, const int* __restrict__ conf,
    float* __restrict__ marks, float* accum)
{
  int lane = threadIdx.x & 63, wv = threadIdx.x >> 6;
  int sub = lane & 15, grp = lane >> 4;
  __shared__ float sred[4];
  float acc1 = 0.f;
  for (int gblk = blockIdx.x; gblk < MROWG; gblk += MGRID) {
    int row = gblk * 16 + wv * 4 + grp;
    const float* cp = class_p + (size_t)row * NC;
    float v[6];
    #pragma unroll
    for (int k = 0; k < 6; k++) {
      int c = sub + 16 * k;
      v[k] = (c < NC) ? cp[c] : -INFINITY;
    }
    float m = v[0];
    #pragma unroll
    for (int k = 1; k < 6; k++) m = fmaxf(m, v[k]);
    #pragma unroll
    for (int o = 1; o < 16; o <<= 1) m = fmaxf(m, __shfl_xor(m, o));
    float s = 0.f;
    #pragma unroll
    for (int k = 0; k < 6; k++) s += __expf(v[k] - m);
    #pragma unroll
    for (int o = 1; o < 16; o <<= 1) s += __shfl_xor(s, o);
    float lse = m + __logf(s);
    if (sub == 0) {
      int cf = conf[row];
      marks[row] = (cf != 0) ? 0.f : (lse - v[0]);
      if (cf > 0) acc1 += lse - cp[cf];
    }
  }
  acc1 = wave_sum(acc1);
  if (lane == 0) sred[wv] = acc1;
  __syncthreads();
  if (threadIdx.x == 0)
    atomicAdd(&accum[1], sred[0] + sred[1] + sred[2] + sred[3]);
}

// Per batch, 256 threads x 76 regs: 31-step binary search on uint bits; sum of top-k marks.
__global__ __launch_bounds__(256) void select_kernel(
    const float* __restrict__ marks, const int* __restrict__ nneg_arr, float* accum)
{
  int b = blockIdx.x, tid = threadIdx.x;
  int lane = tid & 63, wid = tid >> 6;
  float v[NBLK];
  #pragma unroll
  for (int i = 0; i < NBLK; i++) {
    int p = i * 256 + tid;
    v[i] = (p < NP) ? marks[b * NP + p] : 0.f;  // pad 0: midpoints > 0, pads never counted
  }
  int k = nneg_arr[b];
  __shared__ unsigned slo, shi;
  __shared__ int wred[4];
  __shared__ float fred[4];
  if (tid == 0) { slo = 0u; shi = 0x7f800000u; }
  __syncthreads();
  while (true) {
    unsigned lo = slo, hi = shi;
    if (hi - lo <= 1u) break;
    unsigned mid = lo + ((hi - lo) >> 1);
    float fmid = __uint_as_float(mid);
    int cnt = 0;
    #pragma unroll
    for (int i = 0; i < NBLK; i++) cnt += (v[i] >= fmid) ? 1 : 0;
    cnt = wave_sum_i(cnt);
    if (lane == 0) wred[wid] = cnt;
    __syncthreads();
    if (tid == 0) {
      int tot = wred[0] + wred[1] + wred[2] + wred[3];
      if (tot >= k) slo = mid; else shi = mid;
    }
    __syncthreads();
  }
  float thr = __uint_as_float(slo);
  float s = 0.f;
  #pragma unroll
  for (int i = 0; i < NBLK; i++) if (v[i] >= thr) s += v[i];
  s = wave_sum(s);
  if (lane == 0) fred[wid] = s;
  __syncthreads();
  if (tid == 0) atomicAdd(&accum[1], fred[0] + fred[1] + fred[2] + fred[3]);
}

// Separable antialiased resize v3. Block = (plane-group of 4, oy-group of 6).
// Each wave owns one plane; 6 output rows per block amortize dispatch + weight setup.
// Horizontal weight table built once per block. Arithmetic identical to v2 -> bit-exact.
__global__ __launch_bounds__(256) void resize_kernel(
    const float* __restrict__ mask_gt, unsigned char* __restrict__ dmp)
{
  int pg = blockIdx.x;         // plane group 0..15
  int tid = threadIdx.x;
  int wv = tid >> 6, lane = tid & 63;
  int bn = pg * 4 + wv;        // plane 0..63

  __shared__ float tmp[4][IW];       // per-wave vertical-pass rows (8800 B)
  __shared__ float s_wx[PWD][9];     // horizontal weights, padded stride 9 (4968 B)
  __shared__ float s_wsx[PWD];
  __shared__ int   s_xlo[PWD];

  const float ks = (float)IH / (float)PHD;  // 550/138

  // horizontal weights: once per block (threads 0..137)
  if (tid < PWD) {
    int ox = tid;
    float sx = (ox + 0.5f) * ks - 0.5f;
    int xlo = (int)ceilf(sx - ks); if (xlo < 0) xlo = 0;
    int xhi = (int)floorf(sx + ks); if (xhi > IW - 1) xhi = IW - 1;
    int nx = xhi - xlo;
    float wsx = 0.f;
    #pragma unroll
    for (int i = 0; i < 8; i++) {
      float w = (i <= nx) ? fmaxf(0.f, 1.f - fabsf(sx - (float)(xlo + i)) / ks) : 0.f;
      s_wx[ox][i] = w; wsx += w;
    }
    s_xlo[ox] = xlo;
    s_wsx[ox] = wsx;
  }
  __syncthreads();

  const float* mg = mask_gt + (size_t)bn * (IH * IW);

  for (int q = 0; q < 6; ++q) {
    int oy = blockIdx.y * 6 + q;   // 0..137 (138 = 23*6)

    // vertical weights: uniform across the block (same oy)
    float sy = (oy + 0.5f) * ks - 0.5f;
    int ylo = (int)ceilf(sy - ks); if (ylo < 0) ylo = 0;
    int yhi = (int)floorf(sy + ks); if (yhi > IH - 1) yhi = IH - 1;
    int ny = yhi - ylo;   // <= 7
    float wy[8]; float wsy = 0.f;
    #pragma unroll
    for (int j = 0; j < 8; j++) {
      float w = (j <= ny) ? fmaxf(0.f, 1.f - fabsf(sy - (float)(ylo + j)) / ks) : 0.f;
      wy[j] = w; wsy += w;
    }

    // vertical pass: wave wv reduces its plane's 8 rows into tmp[wv][.] (float2 loads).
    // Clamped row index + zero weight adds exactly +0.0 -> bit-exact.
    const float* rowp[8];
    #pragma unroll
    for (int j = 0; j < 8; j++) {
      int y = ylo + j; if (y > IH - 1) y = IH - 1;
      rowp[j] = mg + (size_t)y * IW;
    }
    for (int x2 = lane; x2 < IW / 2; x2 += 64) {
      float ax = 0.f, ay = 0.f;
      #pragma unroll
      for (int j = 0; j < 8; j++) {
        float2 v = *(const float2*)(rowp[j] + 2 * x2);
        ax += wy[j] * v.x;
        ay += wy[j] * v.y;
      }
      tmp[wv][2 * x2]     = ax;
      tmp[wv][2 * x2 + 1] = ay;
    }
    __syncthreads();   // LDS write->read visibility (tmp strips are wave-private)

    // horizontal pass + threshold: 138 outputs per wave (its own plane)
    unsigned char* op = dmp + (size_t)bn * NPX + (size_t)oy * PWD;
    for (int ox = lane; ox < PWD; ox += 64) {
      int xlo = s_xlo[ox];
      float vsum = 0.f;
      #pragma unroll
      for (int i = 0; i < 8; i++) {
        int xi = xlo + i; if (xi > IW - 1) xi = IW - 1;
        vsum += s_wx[ox][i] * tmp[wv][xi];
      }
      op[ox] = (vsum > 0.5f * wsy * s_wsx[ox]) ? 1 : 0;
    }
    __syncthreads();   // all reads of tmp done before next q overwrites
  }
}

// MFMA mask loss v2: 128 px/block (2 pixel-subtiles per wave), softplus-based BCE
// (2 trans ops vs 4 incl log1pf libcall), wave-uniform skip of all-out-of-box
// iterations, dead-tile skip when mb < 112.
// Out-of-box / invalid lanes: l_eff = -1e30 => sp = 0 => terms collapse to the
// reference's clamp constants exactly (p clipped to [1e-7, 0.99999988]).
__global__ __launch_bounds__(256) void maskloss_kernel(
    const float* __restrict__ proto_p, const float* __restrict__ coef_p,
    const float* __restrict__ box_gt, const int* __restrict__ pmi,
    const unsigned char* __restrict__ dmp, const int* __restrict__ pos_list,
    const int* __restrict__ npos_arr, const float* __restrict__ scale_arr,
    float* accum)
{
  int b = blockIdx.y, tid = threadIdx.x;
  int wv = tid >> 6, lane = tid & 63;
  __shared__ unsigned short s_coef[112 * NK];  // bf16 bits
  __shared__ float s_x1[112], s_x2[112], s_y1[112], s_y2[112], s_inv[112];
  __shared__ int s_gi[112];
  __shared__ unsigned char s_gtb[128];
  __shared__ float fr[4];
  int np = npos_arr[b];
  int mb = np < 100 ? np : 100;

  // 112*32 = 3584 = 14*256 exactly: explicit unroll so the 14 loads overlap
  #pragma unroll
  for (int it = 0; it < 14; ++it) {
    int i = tid + it * 256;
    int kk = i >> 5, c = i & 31;
    float v = 0.f;
    if (kk < mb) {
      int p = pos_list[b * 128 + kk];
      v = coef_p[((size_t)(b * NP) + p) * NK + c];
    }
    s_coef[i] = f2bf(v);
  }
  if (tid < 112) {
    int kk = tid;
    float x1 = 0.f, x2 = 0.f, y1 = 0.f, y2 = 0.f, inv = 0.f; int gi = 0;
    if (kk < mb) {
      int p = pos_list[b * 128 + kk];
      gi = pmi[b * NP + p];
      const float* g = box_gt + (b * NOBJ + gi) * 4;
      float bx1 = g[0], by1 = g[1], bx2 = g[2], by2 = g[3];
      float ax = bx1 * 138.f, bx = bx2 * 138.f;
      x1 = fminf(ax, bx); x2 = fmaxf(ax, bx);
      x1 = fmaxf(x1 - 1.f, 0.f); x2 = fminf(x2 + 1.f, 138.f);
      float ay = by1 * 138.f, by_ = by2 * 138.f;
      y1 = fminf(ay, by_); y2 = fmaxf(ay, by_);
      y1 = fmaxf(y1 - 1.f, 0.f); y2 = fminf(y2 + 1.f, 138.f);
      inv = 1.f / ((bx2 - bx1) * (by2 - by1));
    }
    s_x1[kk] = x1; s_x2[kk] = x2; s_y1[kk] = y1; s_y2[kk] = y2;
    s_inv[kk] = inv; s_gi[kk] = gi;
  }
  int px0 = blockIdx.x * 128;
  if (tid < 128) {
    int p = px0 + tid;
    unsigned byte = 0;
    if (p < NPX) {
      #pragma unroll
      for (int n = 0; n < NOBJ; n++)
        byte |= ((unsigned)dmp[(size_t)(b * NOBJ + n) * NPX + p]) << n;
    }
    s_gtb[tid] = (unsigned char)byte;
  }
  __syncthreads();

  int m_in = lane & 15, kq = (lane >> 4) * 8;
  v8s bfr[7];
  #pragma unroll
  for (int t = 0; t < 7; ++t)
    bfr[t] = *(const v8s*)&s_coef[(t * 16 + m_in) * NK + kq];

  v8s afr[2];
  #pragma unroll
  for (int u = 0; u < 2; ++u) {
    int pixel_a = px0 + wv * 32 + u * 16 + m_in;
    if (pixel_a > NPX - 1) pixel_a = NPX - 1;
    const float4* ap = (const float4*)(proto_p + ((size_t)b * NPX + pixel_a) * NK + kq);
    float4 a0 = ap[0], a1 = ap[1];
    float f[8] = {a0.x, a0.y, a0.z, a0.w, a1.x, a1.y, a1.z, a1.w};
    #pragma unroll
    for (int j = 0; j < 8; ++j) afr[u][j] = (short)f2bf(f[j]);
  }

  // per-lane epilogue geometry: 8 (u,r) slots, hoisted out of the t-loop
  float fxa[8], fya[8], pva[8];
  int gtb[8];
  #pragma unroll
  for (int e = 0; e < 8; ++e) {
    int pl = wv * 32 + (e >> 2) * 16 + (lane >> 4) * 4 + (e & 3);
    int pixel = px0 + pl;
    int y = pixel / PWD;
    fya[e] = (float)y;
    fxa[e] = (float)(pixel - y * PWD);
    pva[e] = (pixel < NPX) ? 1.f : 0.f;
    gtb[e] = s_gtb[pl];
  }

  const float C_POS   = 16.11809565f;     // -log(1e-7): p at lower clamp, gt=1 term
  const float C_NEGHI = 15.94238515f;     // -log1p(-0.99999988f): p at upper clamp
  const float C_NEGLO = 1.00000005e-07f;  // -log1p(-1e-7f): p at lower clamp, gt=0 term

  float loss = 0.f;
  #pragma unroll
  for (int t = 0; t < 7; ++t) {
    if (t * 16 < mb) {     // dead-tile skip (uniform branch)
      int n = t * 16 + m_in;
      float x1 = s_x1[n], x2 = s_x2[n], y1 = s_y1[n], y2 = s_y2[n], inv = s_inv[n];
      int gi = s_gi[n];
      #pragma unroll
      for (int u = 0; u < 2; ++u) {
        v4f acc = {0.f, 0.f, 0.f, 0.f};
        acc = __builtin_amdgcn_mfma_f32_16x16x32_bf16(afr[u], bfr[t], acc, 0, 0, 0);
        #pragma unroll
        for (int r = 0; r < 4; ++r) {
          int e = u * 4 + r;
          float fx = fxa[e], fy = fya[e];
          bool inb = (fx >= x1) && (fx < x2) && (fy >= y1) && (fy < y2);
          float w = inv * pva[e];
          int g = (gtb[e] >> gi) & 1;
          unsigned long long mk = __ballot(inb);
          if (mk) {
            // bce = gt*min(softplus(-l), CP) + (1-gt)*clamp(softplus(l), CNL, CNH)
            // softplus(-l) = softplus(l) - l ; out-of-box lanes use l=-1e30 -> sp=0
            float l = inb ? acc[r] : -1e30f;
            float el = __expf(-fabsf(l));
            float sp = fmaxf(l, 0.f) + __logf(1.f + el);
            float t1 = fminf(sp - l, C_POS);
            float t2 = fminf(fmaxf(sp, C_NEGLO), C_NEGHI);
            loss += (g ? t1 : t2) * w;
          } else {
            // whole wave out-of-box: constant path, no transcendentals
            loss += (g ? C_POS : C_NEGLO) * w;
          }
        }
      }
    }
  }
  loss = wave_sum(loss);
  if (lane == 0) fr[wv] = loss;
  __syncthreads();
  if (tid == 0) atomicAdd(&accum[2], (fr[0] + fr[1] + fr[2] + fr[3]) * scale_arr[b]);
}

__global__ void finalize_kernel(const float* accum, float* out) {
  out[0] = 1.5f * accum[0] + accum[1] + accum[2] * (6.125f / (138.f * 138.f));
}

extern "C" void kernel_launch(void* const* d_in, const int* in_sizes, int n_in,
                              void* d_out, int out_size, void* d_ws, size_t ws_size,
                              hipStream_t stream) {
  const float* class_p  = (const float*)d_in[0];
  const float* box_p    = (const float*)d_in[1];
  const float* coef_p   = (const float*)d_in[2];
  const float* proto_p  = (const float*)d_in[3];
  const float* priors   = (const float*)d_in[4];
  const float* box_gt   = (const float*)d_in[5];
  const float* mask_gt  = (const float*)d_in[6];
  const int*   class_gt = (const int*)d_in[7];

  char* ws = (char*)d_ws;
  float* prior_max = (float*)(ws + 0);                 // NB*NP f32 = 615936 B
  int*   prior_arg = (int*)(ws + 615936);              // NB*NP i32
  int*   conf      = (int*)(ws + 1231872);             // NB*NP i32
  float* marks     = (float*)(ws + 1847808);           // NB*NP f32
  unsigned char* dmp = (unsigned char*)(ws + 2463744); // NB*NOBJ*NPX u8 = 1218816
  int*   pos_list  = (int*)(ws + 3682560);             // NB*128 i32 = 4096
  int*   npos_arr  = (int*)(ws + 3686656);             // NB i32
  int*   nneg_arr  = (int*)(ws + 3686688);             // NB i32
  float* scale_arr = (float*)(ws + 3686720);           // NB f32
  float* accum     = (float*)(ws + 3686752);           // 4 f32  (memset region start)
  unsigned long long* forced = (unsigned long long*)(ws + 3686768); // NB*NOBJ u64 = 512
  int*   blkcnt    = (int*)(ws + 3687280);             // NB*NBLK i32 = 2432
  (void)in_sizes; (void)n_in; (void)out_size; (void)ws_size;

  // zero accum (16B) + forced (512B) in one memset node
  hipMemsetAsync((void*)accum, 0, 16 + 512, stream);

  {
    dim3 g(NBLK, NB);
    match1_kernel<<<g, 256, 0, stream>>>(priors, box_gt, prior_max, prior_arg, forced);
    conf_kernel<<<g, 256, 0, stream>>>(priors, box_gt, class_gt, box_p,
                                       prior_max, prior_arg, forced, conf, blkcnt, accum);
    scatter_kernel<<<g, 256, 0, stream>>>(conf, blkcnt, pos_list,
                                          npos_arr, nneg_arr, scale_arr);
  }
  mark_kernel<<<MGRID, 256, 0, stream>>>(class_p, conf, marks, accum);
  select_kernel<<<NB, 256, 0, stream>>>(marks, nneg_arr, accum);
  {
    dim3 g(NB * NOBJ / 4, PHD / 6);   // (plane-group, oy-group)
    resize_kernel<<<g, 256, 0, stream>>>(mask_gt, dmp);
  }
  {
    dim3 g((NPX + 127) / 128, NB);
    maskloss_kernel<<<g, 256, 0, stream>>>(proto_p, coef_p, box_gt, prior_arg, dmp,
                                           pos_list, npos_arr, scale_arr, accum);
  }
  finalize_kernel<<<1, 1, 0, stream>>>(accum, (float*)d_out);
}